// Round 1
// baseline (256.575 us; speedup 1.0000x reference)
//
#include <hip/hip_runtime.h>

#define B_SZ 8192
#define C_DIM 128
#define D_DIM 512

// ---------------------------------------------------------------------------
// Kernel 1: ordered top-5 indices per row of feat (8192 x 512), packed into a
// 64-bit key (10 bits per index). One wave (64 lanes) per row; each lane owns
// 8 contiguous values. 5 rounds of wave-argmax with lower-index tiebreak
// (matches jax.lax.top_k ordering). Block 0 thread 0 also zeroes the global
// accumulator (this kernel completes before kernel 2 starts on the stream).
// ---------------------------------------------------------------------------
__global__ __launch_bounds__(256) void topk_keys_kernel(
    const float* __restrict__ feat,
    unsigned long long* __restrict__ keys,
    float* __restrict__ acc)
{
    if (blockIdx.x == 0 && threadIdx.x == 0) *acc = 0.0f;

    const int lane = threadIdx.x & 63;
    const int wv   = threadIdx.x >> 6;
    const int row  = blockIdx.x * 4 + wv;
    const float* f = feat + (size_t)row * D_DIM;

    const int base = lane * 8;
    float v[8];
    float4 a = *reinterpret_cast<const float4*>(f + base);
    float4 b = *reinterpret_cast<const float4*>(f + base + 4);
    v[0]=a.x; v[1]=a.y; v[2]=a.z; v[3]=a.w;
    v[4]=b.x; v[5]=b.y; v[6]=b.z; v[7]=b.w;

    unsigned sel = 0;
    unsigned long long key = 0;
    for (int k = 0; k < 5; ++k) {
        float best = -3.0e38f;
        int  bidx = 0x7fffffff;
        #pragma unroll
        for (int j = 0; j < 8; ++j) {
            if (!((sel >> j) & 1u)) {
                float val = v[j];
                int   idx = base + j;
                if (val > best || (val == best && idx < bidx)) { best = val; bidx = idx; }
            }
        }
        #pragma unroll
        for (int off = 32; off > 0; off >>= 1) {
            float ov = __shfl_xor(best, off);
            int   oi = __shfl_xor(bidx, off);
            if (ov > best || (ov == best && oi < bidx)) { best = ov; bidx = oi; }
        }
        key |= (unsigned long long)(unsigned)bidx << (10 * k);
        if (bidx >= base && bidx < base + 8) sel |= 1u << (bidx - base);
    }
    if (lane == 0) keys[row] = key;
}

// ---------------------------------------------------------------------------
// Kernel 2: fused prod = P @ Q^T (8192x8192x128 fp32), BCE transform, sum.
// 64x64 tile per 256-thread block; K staged in two 64-wide halves.
// LDS layout is transposed [k][m] with XOR swizzle on the 4-float m-group:
//   store A[m][k] at As[k*64 + ((m>>2 ^ (k>>2))<<2) + (m&3)]
// -> scalar transpose-writes are <=2-way (free), b128 reads are conflict-free.
// ---------------------------------------------------------------------------
__global__ __launch_bounds__(256) void bce_tile_kernel(
    const float* __restrict__ P,       // unlabel_prob   (B, 128)
    const float* __restrict__ Q,       // rot_unlabel_prob (B, 128)
    const unsigned long long* __restrict__ keys,
    float* __restrict__ acc)
{
    __shared__ float As[64 * 64];
    __shared__ float Bs[64 * 64];
    __shared__ float wsum[4];

    const int bi = blockIdx.x & 127;
    const int bj = blockIdx.x >> 7;
    const int row0 = bi << 6, col0 = bj << 6;
    const int tid = threadIdx.x;
    const int tx = tid & 15, ty = tid >> 4;

    float accum[4][4];
    #pragma unroll
    for (int r = 0; r < 4; ++r)
        #pragma unroll
        for (int c = 0; c < 4; ++c) accum[r][c] = 0.0f;

    const int kc = tid & 15;    // float4 chunk along k (16 chunks = 64 cols)
    const int m0 = tid >> 4;    // 0..15; rounds add 16

    for (int h = 0; h < 2; ++h) {
        if (h) __syncthreads();             // everyone done reading half 0
        // ---- stage half h: A and B tiles (64 rows x 64 cols each) ----
        #pragma unroll
        for (int r = 0; r < 4; ++r) {
            const int m = m0 + 16 * r;
            const int g = m >> 2, lo = m & 3;
            float4 av = *reinterpret_cast<const float4*>(
                P + (size_t)(row0 + m) * C_DIM + h * 64 + kc * 4);
            float4 bv = *reinterpret_cast<const float4*>(
                Q + (size_t)(col0 + m) * C_DIM + h * 64 + kc * 4);
            const float* ap = reinterpret_cast<const float*>(&av);
            const float* bp = reinterpret_cast<const float*>(&bv);
            #pragma unroll
            for (int j = 0; j < 4; ++j) {
                const int k  = kc * 4 + j;
                const int sw = (((g ^ (k >> 2)) << 2) + lo);
                As[k * 64 + sw] = ap[j];
                Bs[k * 64 + sw] = bp[j];
            }
        }
        __syncthreads();

        // ---- compute: 64 k-steps, 4x4 micro-tile per thread ----
        #pragma unroll
        for (int ks = 0; ks < 16; ++ks) {        // swizzle const per 4 k
            const int aoff = (ty ^ ks) << 2;
            const int boff = (tx ^ ks) << 2;
            #pragma unroll
            for (int j4 = 0; j4 < 4; ++j4) {
                const int k = ks * 4 + j4;
                float4 a4 = *reinterpret_cast<const float4*>(&As[k * 64 + aoff]);
                float4 b4 = *reinterpret_cast<const float4*>(&Bs[k * 64 + boff]);
                const float* ar = reinterpret_cast<const float*>(&a4);
                const float* br = reinterpret_cast<const float*>(&b4);
                #pragma unroll
                for (int r = 0; r < 4; ++r)
                    #pragma unroll
                    for (int c = 0; c < 4; ++c)
                        accum[r][c] = fmaf(ar[r], br[c], accum[r][c]);
            }
        }
    }

    // ---- epilogue: BCE transform + reduce ----
    unsigned long long ki[4], kj[4];
    #pragma unroll
    for (int r = 0; r < 4; ++r) ki[r] = keys[row0 + ty * 4 + r];
    #pragma unroll
    for (int c = 0; c < 4; ++c) kj[c] = keys[col0 + tx * 4 + c];

    float lsum = 0.0f;
    #pragma unroll
    for (int r = 0; r < 4; ++r) {
        #pragma unroll
        for (int c = 0; c < 4; ++c) {
            float p  = accum[r][c];
            bool sim = (ki[r] == kj[c]);
            float x  = sim ? p : (1.0f - p);
            lsum += fmaxf(__logf(x), -100.0f);
        }
    }

    #pragma unroll
    for (int off = 32; off > 0; off >>= 1) lsum += __shfl_xor(lsum, off);
    if ((tid & 63) == 0) wsum[tid >> 6] = lsum;
    __syncthreads();
    if (tid == 0) atomicAdd(acc, wsum[0] + wsum[1] + wsum[2] + wsum[3]);
}

// ---------------------------------------------------------------------------
// Kernel 3: finalize loss = -sum / B^2
// ---------------------------------------------------------------------------
__global__ void finalize_kernel(const float* __restrict__ acc,
                                float* __restrict__ out)
{
    if (threadIdx.x == 0)
        out[0] = -acc[0] / (float)((long long)B_SZ * (long long)B_SZ);
}

extern "C" void kernel_launch(void* const* d_in, const int* in_sizes, int n_in,
                              void* d_out, int out_size, void* d_ws, size_t ws_size,
                              hipStream_t stream)
{
    const float* feat = (const float*)d_in[0];   // unlabel_feat   (8192, 512)
    const float* prob = (const float*)d_in[1];   // unlabel_prob   (8192, 128)
    const float* rot  = (const float*)d_in[2];   // rot_unlabel_prob (8192, 128)
    float* out = (float*)d_out;

    unsigned long long* keys = (unsigned long long*)d_ws;
    float* acc = (float*)((char*)d_ws + (size_t)B_SZ * sizeof(unsigned long long));

    topk_keys_kernel<<<B_SZ / 4, 256, 0, stream>>>(feat, keys, acc);
    bce_tile_kernel<<<(B_SZ / 64) * (B_SZ / 64), 256, 0, stream>>>(prob, rot, keys, acc);
    finalize_kernel<<<1, 64, 0, stream>>>(acc, out);
}

// Round 2
// 87.696 us; speedup vs baseline: 2.9257x; 2.9257x over previous
//
#include <hip/hip_runtime.h>

#define B_SZ 8192
#define C_DIM 128
#define D_DIM 512

typedef __bf16 bf16x8 __attribute__((ext_vector_type(8)));
typedef float  f32x4  __attribute__((ext_vector_type(4)));

// RNE float -> bf16 (inputs are finite positive probabilities; no NaN path)
__device__ inline unsigned int f2bf(float f) {
    unsigned int u = __builtin_bit_cast(unsigned int, f);
    u += 0x7FFFu + ((u >> 16) & 1u);
    return u >> 16;
}

// ---------------------------------------------------------------------------
// Kernel 1: ordered top-5 indices per row of feat (8192 x 512) -> 64-bit key.
// One wave per row; 5 rounds of wave-argmax with lower-index tiebreak.
// Also zeroes the global accumulator (runs before kernel 2 on the stream).
// ---------------------------------------------------------------------------
__global__ __launch_bounds__(256) void topk_keys_kernel(
    const float* __restrict__ feat,
    unsigned long long* __restrict__ keys,
    float* __restrict__ acc)
{
    if (blockIdx.x == 0 && threadIdx.x == 0) *acc = 0.0f;

    const int lane = threadIdx.x & 63;
    const int wv   = threadIdx.x >> 6;
    const int row  = blockIdx.x * 4 + wv;
    const float* f = feat + (size_t)row * D_DIM;

    const int base = lane * 8;
    float v[8];
    float4 a = *reinterpret_cast<const float4*>(f + base);
    float4 b = *reinterpret_cast<const float4*>(f + base + 4);
    v[0]=a.x; v[1]=a.y; v[2]=a.z; v[3]=a.w;
    v[4]=b.x; v[5]=b.y; v[6]=b.z; v[7]=b.w;

    unsigned sel = 0;
    unsigned long long key = 0;
    for (int k = 0; k < 5; ++k) {
        float best = -3.0e38f;
        int  bidx = 0x7fffffff;
        #pragma unroll
        for (int j = 0; j < 8; ++j) {
            if (!((sel >> j) & 1u)) {
                float val = v[j];
                int   idx = base + j;
                if (val > best || (val == best && idx < bidx)) { best = val; bidx = idx; }
            }
        }
        #pragma unroll
        for (int off = 32; off > 0; off >>= 1) {
            float ov = __shfl_xor(best, off);
            int   oi = __shfl_xor(bidx, off);
            if (ov > best || (ov == best && oi < bidx)) { best = ov; bidx = oi; }
        }
        key |= (unsigned long long)(unsigned)bidx << (10 * k);
        if (bidx >= base && bidx < base + 8) sel |= 1u << (bidx - base);
    }
    if (lane == 0) keys[row] = key;
}

// ---------------------------------------------------------------------------
// Kernel 2: fused prod = P @ Q^T via bf16 MFMA, BCE transform, sum.
// 128x128 tile per 256-thread block, full K=128 staged once (64 KB LDS).
// fp32->bf16 conversion fused into staging. LDS is [row][k=128] bf16 with
// XOR swizzle on the 8-ushort (16B) granule: off ^= (row&7)<<3 -> b128 reads
// across 16 rows hit 8 distinct 16B slots (2-way = free).
// MFMA mfma_f32_16x16x32_bf16 layouts (m89-verified):
//   A lane l: row=l&15, k=(l>>4)*8+j   B lane l: col=l&15, k=(l>>4)*8+j
//   D lane l: col=l&15, row=(l>>4)*4+reg
// ---------------------------------------------------------------------------
__global__ __launch_bounds__(256) void bce_tile_kernel(
    const float* __restrict__ P,       // unlabel_prob     (B, 128)
    const float* __restrict__ Q,       // rot_unlabel_prob (B, 128)
    const unsigned long long* __restrict__ keys,
    float* __restrict__ acc)
{
    __shared__ unsigned short As[128 * 128];   // 32 KB
    __shared__ unsigned short Bs[128 * 128];   // 32 KB
    __shared__ float wsum[4];

    const int bi = blockIdx.x & 63;
    const int bj = blockIdx.x >> 6;
    const int row0 = bi << 7, col0 = bj << 7;
    const int tid = threadIdx.x;

    // ---- stage: convert fp32 -> bf16 into swizzled LDS ----
    {
        const int cw = tid & 15;        // 16B chunk along k (16 x 8 bf16 = 128)
        const int r0 = tid >> 4;        // 0..15, step 16
        #pragma unroll
        for (int i = 0; i < 8; ++i) {
            const int rr = r0 + 16 * i;
            const int so = rr * 128 + ((cw * 8) ^ ((rr & 7) << 3));
            float4 a0 = *reinterpret_cast<const float4*>(P + (size_t)(row0 + rr) * C_DIM + cw * 8);
            float4 a1 = *reinterpret_cast<const float4*>(P + (size_t)(row0 + rr) * C_DIM + cw * 8 + 4);
            float4 b0 = *reinterpret_cast<const float4*>(Q + (size_t)(col0 + rr) * C_DIM + cw * 8);
            float4 b1 = *reinterpret_cast<const float4*>(Q + (size_t)(col0 + rr) * C_DIM + cw * 8 + 4);
            uint4 wa, wb;
            wa.x = f2bf(a0.x) | (f2bf(a0.y) << 16);
            wa.y = f2bf(a0.z) | (f2bf(a0.w) << 16);
            wa.z = f2bf(a1.x) | (f2bf(a1.y) << 16);
            wa.w = f2bf(a1.z) | (f2bf(a1.w) << 16);
            wb.x = f2bf(b0.x) | (f2bf(b0.y) << 16);
            wb.y = f2bf(b0.z) | (f2bf(b0.w) << 16);
            wb.z = f2bf(b1.x) | (f2bf(b1.y) << 16);
            wb.w = f2bf(b1.z) | (f2bf(b1.w) << 16);
            *reinterpret_cast<uint4*>(&As[so]) = wa;
            *reinterpret_cast<uint4*>(&Bs[so]) = wb;
        }
    }
    __syncthreads();

    // ---- compute: 4 waves (2x2), each 64x64 output; K=128 in 4 MFMA steps ----
    const int l  = tid & 63;
    const int wv = tid >> 6;
    const int wm = wv >> 1, wn = wv & 1;
    const int g  = l >> 4, q = l & 15;

    f32x4 accf[4][4];
    #pragma unroll
    for (int mi = 0; mi < 4; ++mi)
        #pragma unroll
        for (int ni = 0; ni < 4; ++ni) accf[mi][ni] = (f32x4){0.f, 0.f, 0.f, 0.f};

    #pragma unroll
    for (int ks = 0; ks < 4; ++ks) {
        bf16x8 af[4], bfr[4];
        #pragma unroll
        for (int mi = 0; mi < 4; ++mi) {
            const int rr = wm * 64 + mi * 16 + q;
            af[mi] = *reinterpret_cast<const bf16x8*>(
                &As[rr * 128 + ((ks * 32 + g * 8) ^ ((rr & 7) << 3))]);
        }
        #pragma unroll
        for (int ni = 0; ni < 4; ++ni) {
            const int rr = wn * 64 + ni * 16 + q;
            bfr[ni] = *reinterpret_cast<const bf16x8*>(
                &Bs[rr * 128 + ((ks * 32 + g * 8) ^ ((rr & 7) << 3))]);
        }
        #pragma unroll
        for (int mi = 0; mi < 4; ++mi)
            #pragma unroll
            for (int ni = 0; ni < 4; ++ni)
                accf[mi][ni] = __builtin_amdgcn_mfma_f32_16x16x32_bf16(
                    af[mi], bfr[ni], accf[mi][ni], 0, 0, 0);
    }

    // ---- epilogue: BCE transform + reduce ----
    unsigned long long ki[4][4], kj[4];
    #pragma unroll
    for (int mi = 0; mi < 4; ++mi)
        #pragma unroll
        for (int r = 0; r < 4; ++r)
            ki[mi][r] = keys[row0 + wm * 64 + mi * 16 + g * 4 + r];
    #pragma unroll
    for (int ni = 0; ni < 4; ++ni)
        kj[ni] = keys[col0 + wn * 64 + ni * 16 + q];

    float lsum = 0.0f;
    #pragma unroll
    for (int mi = 0; mi < 4; ++mi) {
        #pragma unroll
        for (int ni = 0; ni < 4; ++ni) {
            #pragma unroll
            for (int r = 0; r < 4; ++r) {
                float p  = accf[mi][ni][r];
                bool sim = (ki[mi][r] == kj[ni]);
                float x  = sim ? p : (1.0f - p);
                lsum += fmaxf(__logf(x), -100.0f);
            }
        }
    }

    #pragma unroll
    for (int off = 32; off > 0; off >>= 1) lsum += __shfl_xor(lsum, off);
    if ((tid & 63) == 0) wsum[tid >> 6] = lsum;
    __syncthreads();
    if (tid == 0) atomicAdd(acc, wsum[0] + wsum[1] + wsum[2] + wsum[3]);
}

// ---------------------------------------------------------------------------
// Kernel 3: finalize loss = -sum / B^2
// ---------------------------------------------------------------------------
__global__ void finalize_kernel(const float* __restrict__ acc,
                                float* __restrict__ out)
{
    if (threadIdx.x == 0)
        out[0] = -acc[0] / (float)((long long)B_SZ * (long long)B_SZ);
}

extern "C" void kernel_launch(void* const* d_in, const int* in_sizes, int n_in,
                              void* d_out, int out_size, void* d_ws, size_t ws_size,
                              hipStream_t stream)
{
    const float* feat = (const float*)d_in[0];   // unlabel_feat     (8192, 512)
    const float* prob = (const float*)d_in[1];   // unlabel_prob     (8192, 128)
    const float* rot  = (const float*)d_in[2];   // rot_unlabel_prob (8192, 128)
    float* out = (float*)d_out;

    unsigned long long* keys = (unsigned long long*)d_ws;
    float* acc = (float*)((char*)d_ws + (size_t)B_SZ * sizeof(unsigned long long));

    topk_keys_kernel<<<B_SZ / 4, 256, 0, stream>>>(feat, keys, acc);
    bce_tile_kernel<<<(B_SZ / 128) * (B_SZ / 128), 256, 0, stream>>>(prob, rot, keys, acc);
    finalize_kernel<<<1, 64, 0, stream>>>(acc, out);
}